// Round 10
// baseline (84.349 us; speedup 1.0000x reference)
//
#include <hip/hip_runtime.h>
#include <hip/hip_bf16.h>

typedef __attribute__((ext_vector_type(8))) short short8;
typedef __attribute__((ext_vector_type(4))) float f32x4;
typedef __attribute__((ext_vector_type(4))) unsigned int u32x4;
typedef __attribute__((ext_vector_type(2))) unsigned int u32x2;

#define DFEAT 128
#define LDW 136   // Wt row stride in shorts

__device__ __forceinline__ unsigned short f2bf(float f) {
    unsigned int u = __float_as_uint(f);
    u += 0x7FFFu + ((u >> 16) & 1u);   // round-nearest-even
    return (unsigned short)(u >> 16);
}
// packed f32x2 -> bf16x2, RNE (gfx950 v_cvt_pk_bf16_f32)
__device__ __forceinline__ unsigned int cvt2(float lo, float hi) {
    unsigned int r;
    asm("v_cvt_pk_bf16_f32 %0, %1, %2" : "=v"(r) : "v"(lo), "v"(hi));
    return r;
}
__device__ __forceinline__ float bf2f(unsigned int bits) {
    return __uint_as_float(bits << 16);
}

// Issue 8x dwordx4 strip loads via asm volatile: the compiler cannot sink or
// fold these (rounds 6/7 proved C++-level prefetch gets defeated). Data valid
// only after an explicit s_waitcnt vmcnt with exact in-order accounting.
__device__ __forceinline__ void pf_issue(f32x4 (&pf)[8], const float* zr) {
    asm volatile("global_load_dwordx4 %0, %1, off"            : "=&v"(pf[0]) : "v"(zr) : "memory");
    asm volatile("global_load_dwordx4 %0, %1, off offset:16"  : "=&v"(pf[1]) : "v"(zr) : "memory");
    asm volatile("global_load_dwordx4 %0, %1, off offset:128" : "=&v"(pf[2]) : "v"(zr) : "memory");
    asm volatile("global_load_dwordx4 %0, %1, off offset:144" : "=&v"(pf[3]) : "v"(zr) : "memory");
    asm volatile("global_load_dwordx4 %0, %1, off offset:256" : "=&v"(pf[4]) : "v"(zr) : "memory");
    asm volatile("global_load_dwordx4 %0, %1, off offset:272" : "=&v"(pf[5]) : "v"(zr) : "memory");
    asm volatile("global_load_dwordx4 %0, %1, off offset:384" : "=&v"(pf[6]) : "v"(zr) : "memory");
    asm volatile("global_load_dwordx4 %0, %1, off offset:400" : "=&v"(pf[7]) : "v"(zr) : "memory");
}

// Phase 1: A[n][:] = zi[n] @ W1[0:128][:] + b1 (table 0); B analogous (table 1).
// One wave per 16x128 strip; swapped MFMA operands -> packed 8B stores.
// TWO asm-pinned prefetch buffers (pfA/pfB) = 2-deep pipeline: the load for
// strip n+2 is in flight while strips n and n+1 compute. vmcnt is in-order,
// so waits count ops issued AFTER the target loads. Loads are ALWAYS issued
// (clamped address) so issue counts stay uniform:
//   prologue: pfA(8), pfB(8)
//   peel A : vmcnt(8)  [after pfA: pfB=8]
//   peel B : vmcnt(16) [after pfB: pfA'+storesA = 16]
//   steady : vmcnt(24) [after pfX: 8 stores + 8 loads + 8 stores]
// Guarded (skipped) tail stores only happen in phases strictly after the
// last executed wait (sB garbage => next sA = sB+nw also garbage => exit).
__global__ __launch_bounds__(256) void node_gemm(
    const float* __restrict__ zi, const float* __restrict__ zj,
    const float* __restrict__ W1, const float* __restrict__ b1,
    unsigned short* __restrict__ Aout, unsigned short* __restrict__ Bout,
    int nN)
{
    __shared__ unsigned short Wt[128][LDW];   // Wt[col][k] bf16
    __shared__ float bias_lds[128];
    const int table = blockIdx.y;
    const float* __restrict__ z = table ? zj : zi;
    unsigned short* __restrict__ outp = table ? Bout : Aout;

    for (int idx = threadIdx.x; idx < 128 * 128; idx += 256) {
        int c = idx & 127, k = idx >> 7;
        Wt[c][k] = f2bf(W1[(size_t)(table * 128 + k) * DFEAT + c]);
    }
    if (threadIdx.x < 128) bias_lds[threadIdx.x] = table ? 0.f : b1[threadIdx.x];
    __syncthreads();

    const int lane = threadIdx.x & 63;
    const int l15  = lane & 15;
    const int kg   = lane >> 4;          // 0..3
    const int wv = blockIdx.x * 4 + (threadIdx.x >> 6);
    const int nw = gridDim.x * 4;
    const int nStrips = (nN + 15) >> 4;
    if (wv >= nStrips) return;           // after last barrier: safe

    auto zaddr = [&](int s) {
        int row = s * 16 + l15;
        if (row >= nN) row = nN - 1;     // clamp: issued loads always legal
        return z + (size_t)row * DFEAT + kg * 8;
    };

    f32x4 pfA[8], pfB[8];
    int sA = wv, sB = wv + nw;
    pf_issue(pfA, zaddr(sA));
    pf_issue(pfB, zaddr(sB));

    auto process = [&](f32x4 (&pf)[8], int s, int spre) {
        // 1) convert this strip fp32 -> bf16 fragments (frees pf)
        short8 bf[4];
#pragma unroll
        for (int kk = 0; kk < 4; ++kk) {
            union { unsigned int u[4]; short8 s8; } cv;
            cv.u[0] = cvt2(pf[2 * kk][0], pf[2 * kk][1]);
            cv.u[1] = cvt2(pf[2 * kk][2], pf[2 * kk][3]);
            cv.u[2] = cvt2(pf[2 * kk + 1][0], pf[2 * kk + 1][1]);
            cv.u[3] = cvt2(pf[2 * kk + 1][2], pf[2 * kk + 1][3]);
            bf[kk] = cv.s8;
        }
        __builtin_amdgcn_sched_barrier(0);
        // 2) issue strip s+2nw into the SAME buffer (always: uniform counts)
        pf_issue(pf, zaddr(spre));
        __builtin_amdgcn_sched_barrier(0);
        // 3) MFMA in two 4-tile halves (acc = 16 VGPRs) + guarded stores
        int row = s * 16 + l15;
        unsigned short* op = outp + (size_t)row * DFEAT + kg * 4;
#pragma unroll
        for (int h = 0; h < 2; ++h) {
            f32x4 acc[4];
#pragma unroll
            for (int ci = 0; ci < 4; ++ci)
                acc[ci] = *(const f32x4*)&bias_lds[(h * 4 + ci) * 16 + kg * 4];
#pragma unroll
            for (int kk = 0; kk < 4; ++kk) {
#pragma unroll
                for (int ci = 0; ci < 4; ++ci) {
                    short8 a = *(const short8*)&Wt[(h * 4 + ci) * 16 + l15][kk * 32 + kg * 8];
                    acc[ci] = __builtin_amdgcn_mfma_f32_16x16x32_bf16(a, bf[kk], acc[ci], 0, 0, 0);
                }
            }
            if (row < nN) {
#pragma unroll
                for (int ci = 0; ci < 4; ++ci) {
                    u32x2 v;
                    v[0] = cvt2(acc[ci][0], acc[ci][1]);
                    v[1] = cvt2(acc[ci][2], acc[ci][3]);
                    *(u32x2*)(op + (h * 4 + ci) * 16) = v;
                }
            }
        }
    };

    // peel A
    asm volatile("s_waitcnt vmcnt(8)" ::: "memory");
    __builtin_amdgcn_sched_barrier(0);
    process(pfA, sA, sA + 2 * nw);
    // peel B
    asm volatile("s_waitcnt vmcnt(16)" ::: "memory");
    __builtin_amdgcn_sched_barrier(0);
    process(pfB, sB, sB + 2 * nw);
    sA += 2 * nw; sB += 2 * nw;

    while (sA < nStrips) {
        asm volatile("s_waitcnt vmcnt(24)" ::: "memory");
        __builtin_amdgcn_sched_barrier(0);
        process(pfA, sA, sA + 2 * nw);
        sA += 2 * nw;
        asm volatile("s_waitcnt vmcnt(24)" ::: "memory");
        __builtin_amdgcn_sched_barrier(0);
        process(pfB, sB, sB + 2 * nw);
        sB += 2 * nw;
    }
}

// Phase 2 (round-6 verbatim, measured ~45us, at random-gather roofline):
// 16 lanes/edge, 8 edges/wave/iter (2 quads unrolled).
__global__ __launch_bounds__(256) void edge_kernel(
    const unsigned short* __restrict__ A, const unsigned short* __restrict__ B,
    const int* __restrict__ src, const int* __restrict__ dst,
    const float* __restrict__ W3, const float* __restrict__ b3,
    float* __restrict__ out, int nE)
{
    const int lane = threadIdx.x & 63;
    const int sub  = lane & 15;
    const int grp  = lane >> 4;

    float w3v[8];
#pragma unroll
    for (int j = 0; j < 8; ++j) w3v[j] = W3[sub * 8 + j];
    const float bb = b3[0];

    int wv = blockIdx.x * 4 + (threadIdx.x >> 6);
    int nw = gridDim.x * 4;

    for (int base = wv * 8; base < nE; base += nw * 8) {
        int e0 = base + grp;
        int e1 = base + 4 + grp;
        bool v0 = e0 < nE, v1 = e1 < nE;
        int s0 = v0 ? src[e0] : 0, d0 = v0 ? dst[e0] : 0;
        int s1 = v1 ? src[e1] : 0, d1 = v1 ? dst[e1] : 0;

        const u32x4* pa0 = (const u32x4*)(A + (size_t)s0 * DFEAT + sub * 8);
        const u32x4* pb0 = (const u32x4*)(B + (size_t)d0 * DFEAT + sub * 8);
        const u32x4* pa1 = (const u32x4*)(A + (size_t)s1 * DFEAT + sub * 8);
        const u32x4* pb1 = (const u32x4*)(B + (size_t)d1 * DFEAT + sub * 8);
        u32x4 av0 = *pa0, bv0 = *pb0;
        u32x4 av1 = *pa1, bv1 = *pb1;

        float p0 = 0.f, p1 = 0.f;
#pragma unroll
        for (int w = 0; w < 4; ++w) {
            float x0 = fmaxf(bf2f(av0[w] & 0xFFFFu) + bf2f(bv0[w] & 0xFFFFu), 0.f);
            float x1 = fmaxf(bf2f(av0[w] >> 16)     + bf2f(bv0[w] >> 16),     0.f);
            p0 = fmaf(x0, w3v[w * 2], p0);
            p0 = fmaf(x1, w3v[w * 2 + 1], p0);
            float y0 = fmaxf(bf2f(av1[w] & 0xFFFFu) + bf2f(bv1[w] & 0xFFFFu), 0.f);
            float y1 = fmaxf(bf2f(av1[w] >> 16)     + bf2f(bv1[w] >> 16),     0.f);
            p1 = fmaf(y0, w3v[w * 2], p1);
            p1 = fmaf(y1, w3v[w * 2 + 1], p1);
        }
#pragma unroll
        for (int off = 8; off > 0; off >>= 1) {
            p0 += __shfl_xor(p0, off, 64);
            p1 += __shfl_xor(p1, off, 64);
        }
        if (sub == 0) {
            if (v0) out[e0] = 1.f / (1.f + __expf(-(p0 + bb)));
            if (v1) out[e1] = 1.f / (1.f + __expf(-(p1 + bb)));
        }
    }
}

// Fallback (only if d_ws too small): direct per-edge dense compute. Slow, correct.
__global__ __launch_bounds__(256) void fallback_kernel(
    const float* __restrict__ zi, const float* __restrict__ zj,
    const int* __restrict__ src, const int* __restrict__ dst,
    const float* __restrict__ W1, const float* __restrict__ b1,
    const float* __restrict__ W3, const float* __restrict__ b3,
    float* __restrict__ out, int nE)
{
    int e = blockIdx.x * blockDim.x + threadIdx.x;
    if (e >= nE) return;
    const float* a = zi + (size_t)src[e] * DFEAT;
    const float* b = zj + (size_t)dst[e] * DFEAT;
    float logit = b3[0];
    for (int h = 0; h < 128; ++h) {
        float acc = b1[h];
        for (int k = 0; k < 128; ++k) acc = fmaf(a[k], W1[(size_t)k * 128 + h], acc);
        for (int k = 0; k < 128; ++k) acc = fmaf(b[k], W1[(size_t)(128 + k) * 128 + h], acc);
        if (acc > 0.f) logit = fmaf(acc, W3[h], logit);
    }
    out[e] = 1.f / (1.f + __expf(-logit));
}

extern "C" void kernel_launch(void* const* d_in, const int* in_sizes, int n_in,
                              void* d_out, int out_size, void* d_ws, size_t ws_size,
                              hipStream_t stream) {
    const float* zi = (const float*)d_in[0];
    const float* zj = (const float*)d_in[1];
    const int*  src = (const int*)d_in[2];
    const int*  dst = (const int*)d_in[3];
    const float* W1 = (const float*)d_in[4];
    const float* b1 = (const float*)d_in[5];
    const float* W3 = (const float*)d_in[6];
    const float* b3 = (const float*)d_in[7];
    float* out = (float*)d_out;

    int nN = in_sizes[0] / DFEAT;
    int nE = in_sizes[2];
    size_t abytes = (size_t)nN * DFEAT * sizeof(unsigned short);

    if (ws_size >= 2 * abytes) {
        unsigned short* A = (unsigned short*)d_ws;
        unsigned short* B = A + (size_t)nN * DFEAT;
        // 512x2 = 1024 blocks = 4/CU (16 waves/CU); ~3 strips/wave, 2-deep pipe
        dim3 g1(512, 2, 1);
        node_gemm<<<g1, 256, 0, stream>>>(zi, zj, W1, b1, A, B, nN);
        edge_kernel<<<2048, 256, 0, stream>>>(A, B, src, dst, W3, b3, out, nE);
    } else {
        fallback_kernel<<<(nE + 255) / 256, 256, 0, stream>>>(
            zi, zj, src, dst, W1, b1, W3, b3, out, nE);
    }
}

// Round 11
// 75.946 us; speedup vs baseline: 1.1106x; 1.1106x over previous
//
#include <hip/hip_runtime.h>
#include <hip/hip_bf16.h>

typedef __attribute__((ext_vector_type(8))) short short8;
typedef __attribute__((ext_vector_type(4))) float f32x4;
typedef __attribute__((ext_vector_type(4))) unsigned int u32x4;
typedef __attribute__((ext_vector_type(2))) unsigned int u32x2;

#define DFEAT 128
#define LDW 136    // W^T row stride (shorts)
#define LDZ 136    // z-tile row stride (shorts): 272B rows -> <=2-way banks on b128

__device__ __forceinline__ unsigned short f2bf(float f) {
    unsigned int u = __float_as_uint(f);
    u += 0x7FFFu + ((u >> 16) & 1u);   // round-nearest-even
    return (unsigned short)(u >> 16);
}
// packed f32x2 -> bf16x2, RNE (gfx950 v_cvt_pk_bf16_f32)
__device__ __forceinline__ unsigned int cvt2(float lo, float hi) {
    unsigned int r;
    asm("v_cvt_pk_bf16_f32 %0, %1, %2" : "=v"(r) : "v"(lo), "v"(hi));
    return r;
}
__device__ __forceinline__ float bf2f(unsigned int bits) {
    return __uint_as_float(bits << 16);
}

// node_gemm v6 (cooperative strips):
//   block = 4 waves; a BLOCK owns each 16x128 strip (grid-stride).
//   Wave w owns output cols [w*32, w*32+32): its 8 W^T fragments hoisted to
//   32 VGPRs ONCE (no per-strip W LDS reads). z staged per strip into a
//   bf16 LDS tile [16][LDZ] (double-buffered, 8.7KB): thread t loads 32B of
//   the NEXT strip via 2 asm-pinned dwordx4 (issued before compute of the
//   current strip), cvt_pk's them, one ds_write_b128.
// VMEM accounting per loop iter (in-order queue): 2 loads, then epilogue's
//   2 stores, then s_waitcnt vmcnt(2) -> retires exactly the 2 loads.
//   Loads are ALWAYS issued (clamped addr) so counts stay uniform; epilogue
//   store count is uniform because nN % 16 == 0 here (100000).
__global__ __launch_bounds__(256) void node_gemm(
    const float* __restrict__ zi, const float* __restrict__ zj,
    const float* __restrict__ W1, const float* __restrict__ b1,
    unsigned short* __restrict__ Aout, unsigned short* __restrict__ Bout,
    int nN)
{
    union SMem {
        unsigned short wt[128][LDW];     // 34816 B, W^T staging (prologue only)
        unsigned short zb[2][16][LDZ];   //  8704 B, z double buffer (reuses space)
    };
    __shared__ SMem sm;

    const int table = blockIdx.y;
    const float* __restrict__ z = table ? zj : zi;
    unsigned short* __restrict__ outp = table ? Bout : Aout;
    const int tid = threadIdx.x;

    // --- prologue: stage W-half transposed as bf16 (coalesced) ---
    for (int idx = tid; idx < 128 * 128; idx += 256) {
        int c = idx & 127, k = idx >> 7;
        sm.wt[c][k] = f2bf(W1[(size_t)(table * 128 + k) * DFEAT + c]);
    }
    __syncthreads();

    const int lane = tid & 63;
    const int l15  = lane & 15;
    const int kg   = lane >> 4;          // 0..3
    const int w    = tid >> 6;           // wave id 0..3
    const int cbase = w * 32;

    // --- hoist this wave's W^T fragments (strip-invariant, 32 VGPRs) ---
    short8 wf[2][4];
#pragma unroll
    for (int ci = 0; ci < 2; ++ci)
#pragma unroll
        for (int kk = 0; kk < 4; ++kk)
            wf[ci][kk] = *(const short8*)&sm.wt[cbase + ci * 16 + l15][kk * 32 + kg * 8];

    f32x4 biasv[2];
    if (table == 0) {
#pragma unroll
        for (int ci = 0; ci < 2; ++ci)
            biasv[ci] = *(const f32x4*)&b1[cbase + ci * 16 + kg * 4];
    } else {
        biasv[0] = (f32x4){0.f, 0.f, 0.f, 0.f};
        biasv[1] = (f32x4){0.f, 0.f, 0.f, 0.f};
    }
    __syncthreads();   // wt reads done; zb may overwrite

    const int nStrips = (nN + 15) >> 4;
    const int G = gridDim.x;
    const int r    = tid >> 4;           // staging row 0..15
    const int coff = (tid & 15) * 8;     // staging col (floats)

    auto gaddr = [&](int s) {
        int row = s * 16 + r;
        if (row >= nN) row = nN - 1;     // clamp: always-legal issue
        return z + (size_t)row * DFEAT + coff;
    };

    f32x4 t0, t1;
    auto issue = [&](int s) {
        const float* gp = gaddr(s);
        asm volatile("global_load_dwordx4 %0, %1, off"           : "=&v"(t0) : "v"(gp) : "memory");
        asm volatile("global_load_dwordx4 %0, %1, off offset:16" : "=&v"(t1) : "v"(gp) : "memory");
    };
    auto write_tile = [&](int buf) {
        u32x4 v;
        v[0] = cvt2(t0[0], t0[1]);
        v[1] = cvt2(t0[2], t0[3]);
        v[2] = cvt2(t1[0], t1[1]);
        v[3] = cvt2(t1[2], t1[3]);
        *(u32x4*)&sm.zb[buf][r][coff] = v;
    };

    int s = blockIdx.x;
    int buf = 0;
    // prologue stage: strip s -> buf0
    issue(s);
    asm volatile("s_waitcnt vmcnt(0)" ::: "memory");
    __builtin_amdgcn_sched_barrier(0);
    write_tile(0);
    __syncthreads();

    while (s < nStrips) {
        // 1) issue next strip's loads (always; clamped)
        issue(s + G);

        // 2) compute current strip from sm.zb[buf]
        f32x4 acc0 = biasv[0], acc1 = biasv[1];
#pragma unroll
        for (int kk = 0; kk < 4; ++kk) {
            short8 zf = *(const short8*)&sm.zb[buf][l15][kk * 32 + kg * 8];
            acc0 = __builtin_amdgcn_mfma_f32_16x16x32_bf16(wf[0][kk], zf, acc0, 0, 0, 0);
            acc1 = __builtin_amdgcn_mfma_f32_16x16x32_bf16(wf[1][kk], zf, acc1, 0, 0, 0);
        }
        int row = s * 16 + l15;
        if (row < nN) {
            unsigned short* op = outp + (size_t)row * DFEAT + cbase + kg * 4;
            u32x2 v0; v0[0] = cvt2(acc0[0], acc0[1]); v0[1] = cvt2(acc0[2], acc0[3]);
            *(u32x2*)op = v0;
            u32x2 v1; v1[0] = cvt2(acc1[0], acc1[1]); v1[1] = cvt2(acc1[2], acc1[3]);
            *(u32x2*)(op + 16) = v1;
        }

        // 3) retire the 2 loads (2 stores younger stay in flight), write tile
        asm volatile("s_waitcnt vmcnt(2)" ::: "memory");
        __builtin_amdgcn_sched_barrier(0);
        write_tile(buf ^ 1);
        __syncthreads();
        buf ^= 1;
        s += G;
    }
}

// Phase 2 (round-6 verbatim, measured ~45us, at random-gather roofline):
// 16 lanes/edge, 8 edges/wave/iter (2 quads unrolled).
__global__ __launch_bounds__(256) void edge_kernel(
    const unsigned short* __restrict__ A, const unsigned short* __restrict__ B,
    const int* __restrict__ src, const int* __restrict__ dst,
    const float* __restrict__ W3, const float* __restrict__ b3,
    float* __restrict__ out, int nE)
{
    const int lane = threadIdx.x & 63;
    const int sub  = lane & 15;
    const int grp  = lane >> 4;

    float w3v[8];
#pragma unroll
    for (int j = 0; j < 8; ++j) w3v[j] = W3[sub * 8 + j];
    const float bb = b3[0];

    int wv = blockIdx.x * 4 + (threadIdx.x >> 6);
    int nw = gridDim.x * 4;

    for (int base = wv * 8; base < nE; base += nw * 8) {
        int e0 = base + grp;
        int e1 = base + 4 + grp;
        bool v0 = e0 < nE, v1 = e1 < nE;
        int s0 = v0 ? src[e0] : 0, d0 = v0 ? dst[e0] : 0;
        int s1 = v1 ? src[e1] : 0, d1 = v1 ? dst[e1] : 0;

        const u32x4* pa0 = (const u32x4*)(A + (size_t)s0 * DFEAT + sub * 8);
        const u32x4* pb0 = (const u32x4*)(B + (size_t)d0 * DFEAT + sub * 8);
        const u32x4* pa1 = (const u32x4*)(A + (size_t)s1 * DFEAT + sub * 8);
        const u32x4* pb1 = (const u32x4*)(B + (size_t)d1 * DFEAT + sub * 8);
        u32x4 av0 = *pa0, bv0 = *pb0;
        u32x4 av1 = *pa1, bv1 = *pb1;

        float p0 = 0.f, p1 = 0.f;
#pragma unroll
        for (int w = 0; w < 4; ++w) {
            float x0 = fmaxf(bf2f(av0[w] & 0xFFFFu) + bf2f(bv0[w] & 0xFFFFu), 0.f);
            float x1 = fmaxf(bf2f(av0[w] >> 16)     + bf2f(bv0[w] >> 16),     0.f);
            p0 = fmaf(x0, w3v[w * 2], p0);
            p0 = fmaf(x1, w3v[w * 2 + 1], p0);
            float y0 = fmaxf(bf2f(av1[w] & 0xFFFFu) + bf2f(bv1[w] & 0xFFFFu), 0.f);
            float y1 = fmaxf(bf2f(av1[w] >> 16)     + bf2f(bv1[w] >> 16),     0.f);
            p1 = fmaf(y0, w3v[w * 2], p1);
            p1 = fmaf(y1, w3v[w * 2 + 1], p1);
        }
#pragma unroll
        for (int off = 8; off > 0; off >>= 1) {
            p0 += __shfl_xor(p0, off, 64);
            p1 += __shfl_xor(p1, off, 64);
        }
        if (sub == 0) {
            if (v0) out[e0] = 1.f / (1.f + __expf(-(p0 + bb)));
            if (v1) out[e1] = 1.f / (1.f + __expf(-(p1 + bb)));
        }
    }
}

// Fallback (only if d_ws too small): direct per-edge dense compute. Slow, correct.
__global__ __launch_bounds__(256) void fallback_kernel(
    const float* __restrict__ zi, const float* __restrict__ zj,
    const int* __restrict__ src, const int* __restrict__ dst,
    const float* __restrict__ W1, const float* __restrict__ b1,
    const float* __restrict__ W3, const float* __restrict__ b3,
    float* __restrict__ out, int nE)
{
    int e = blockIdx.x * blockDim.x + threadIdx.x;
    if (e >= nE) return;
    const float* a = zi + (size_t)src[e] * DFEAT;
    const float* b = zj + (size_t)dst[e] * DFEAT;
    float logit = b3[0];
    for (int h = 0; h < 128; ++h) {
        float acc = b1[h];
        for (int k = 0; k < 128; ++k) acc = fmaf(a[k], W1[(size_t)k * 128 + h], acc);
        for (int k = 0; k < 128; ++k) acc = fmaf(b[k], W1[(size_t)(128 + k) * 128 + h], acc);
        if (acc > 0.f) logit = fmaf(acc, W3[h], logit);
    }
    out[e] = 1.f / (1.f + __expf(-logit));
}

extern "C" void kernel_launch(void* const* d_in, const int* in_sizes, int n_in,
                              void* d_out, int out_size, void* d_ws, size_t ws_size,
                              hipStream_t stream) {
    const float* zi = (const float*)d_in[0];
    const float* zj = (const float*)d_in[1];
    const int*  src = (const int*)d_in[2];
    const int*  dst = (const int*)d_in[3];
    const float* W1 = (const float*)d_in[4];
    const float* b1 = (const float*)d_in[5];
    const float* W3 = (const float*)d_in[6];
    const float* b3 = (const float*)d_in[7];
    float* out = (float*)d_out;

    int nN = in_sizes[0] / DFEAT;
    int nE = in_sizes[2];
    size_t abytes = (size_t)nN * DFEAT * sizeof(unsigned short);

    if (ws_size >= 2 * abytes && (nN & 15) == 0) {
        unsigned short* A = (unsigned short*)d_ws;
        unsigned short* B = A + (size_t)nN * DFEAT;
        // 512x2 = 1024 blocks = 4/CU; block-per-strip, ~12 strips/block
        dim3 g1(512, 2, 1);
        node_gemm<<<g1, 256, 0, stream>>>(zi, zj, W1, b1, A, B, nN);
        edge_kernel<<<2048, 256, 0, stream>>>(A, B, src, dst, W3, b3, out, nE);
    } else {
        fallback_kernel<<<(nE + 255) / 256, 256, 0, stream>>>(
            zi, zj, src, dst, W1, b1, W3, b3, out, nE);
    }
}